// Round 1
// baseline (2495.106 us; speedup 1.0000x reference)
//
#include <hip/hip_runtime.h>
#include <hip/hip_bf16.h>
#include <math.h>

#define DIMV   768
#define BATCH  64
#define KEEPT  49
#define MTOK   (BATCH*KEEPT)   // 3136
#define NHEADS 12
#define DHEAD  64
#define FFV    3072
#define NDEPTH 12

typedef short short8 __attribute__((ext_vector_type(8)));
typedef float floatx4 __attribute__((ext_vector_type(4)));
typedef unsigned short ushort;
typedef unsigned short ushortx8 __attribute__((ext_vector_type(8)));

__device__ __forceinline__ ushort f2bf(float f) {
  __hip_bfloat16 h = __float2bfloat16(f);
  return *(ushort*)&h;
}

// ---------------------------------------------------------------------------
__device__ __forceinline__ void async_cp16(const void* g, void* l) {
  __builtin_amdgcn_global_load_lds((const __attribute__((address_space(1))) void*)g,
                                   (__attribute__((address_space(3))) void*)l,
                                   16, 0, 0);
}

// ---------------------------------------------------------------------------
// gather kept-patch pixels into (MTOK x 768) bf16 matrix
__global__ __launch_bounds__(256) void gather_patches(
    const float* __restrict__ inp, const int* __restrict__ mask,
    __hip_bfloat16* __restrict__ apix)
{
  int gid = blockIdx.x * 256 + threadIdx.x;
  if (gid >= MTOK * DIMV) return;
  int r = gid / DIMV, k = gid - r * DIMV;
  int b = r / KEEPT, t = r - b * KEEPT;
  int j = mask[t];
  j = j < 0 ? 0 : (j > 196 ? 196 : j);   // JAX clamps OOB gather indices
  float v = 0.f;
  if (j > 0) {
    int p  = j - 1, py = p / 14, px = p - py * 14;
    int ky = k / 48, rem = k - ky * 48, kx = rem / 3, c = rem - kx * 3;
    v = inp[(((b * 224) + py * 16 + ky) * 224 + px * 16 + kx) * 3 + c];
  }
  apix[gid] = __float2bfloat16(v);
}

// ---------------------------------------------------------------------------
// row layernorm fp32 -> bf16, eps=1e-9
__global__ __launch_bounds__(256) void layernorm_k(
    const float* __restrict__ x, const float* __restrict__ sc,
    const float* __restrict__ bi, __hip_bfloat16* __restrict__ out)
{
  __shared__ float red[8];
  int r = blockIdx.x;
  const float* xr = x + (size_t)r * DIMV;
  int t = threadIdx.x;
  float v[3];
  float s = 0.f, ss = 0.f;
#pragma unroll
  for (int i = 0; i < 3; i++) {
    float a = xr[t + i * 256];
    v[i] = a; s += a; ss += a * a;
  }
#pragma unroll
  for (int off = 32; off > 0; off >>= 1) {
    s  += __shfl_down(s,  off, 64);
    ss += __shfl_down(ss, off, 64);
  }
  int wave = t >> 6, lane = t & 63;
  if (lane == 0) { red[wave] = s; red[4 + wave] = ss; }
  __syncthreads();
  if (t == 0) {
    float a  = red[0] + red[1] + red[2] + red[3];
    float b2 = red[4] + red[5] + red[6] + red[7];
    float m  = a * (1.f / DIMV);
    float var = b2 * (1.f / DIMV) - m * m;
    red[0] = m;
    red[1] = rsqrtf(var + 1e-9f);
  }
  __syncthreads();
  float m = red[0], rs = red[1];
  __hip_bfloat16* outr = out + (size_t)r * DIMV;
#pragma unroll
  for (int i = 0; i < 3; i++) {
    int d = t + i * 256;
    outr[d] = __float2bfloat16((v[i] - m) * rs * sc[d] + bi[d]);
  }
}

// ---------------------------------------------------------------------------
// 64x64-tile fp32 -> bf16 transpose (dst[c][r] = bf16(src[r][c])):
// float4 reads into 64x65 fp32 LDS; output stage: each thread owns one dst
// column (c = tid>>2) and a 16-row half-chunk pair, emitting two 16B ushort8
// stores. LDS column reads hit bank (r+c)%32 -> 2-way (free).
__device__ __forceinline__ void transpose_tile64(
    const float* __restrict__ src, __hip_bfloat16* __restrict__ dst,
    int R, int C, int tr, int tcc)
{
  __shared__ float lds[64][65];
  const int tid = threadIdx.x;
  const int r0 = tr * 64, c0 = tcc * 64;
  const int lr = tid >> 4, lc4 = (tid & 15) * 4;
#pragma unroll
  for (int p = 0; p < 4; p++) {
    float4 v = *(const float4*)(src + (size_t)(r0 + p * 16 + lr) * C + c0 + lc4);
    lds[p * 16 + lr][lc4 + 0] = v.x;
    lds[p * 16 + lr][lc4 + 1] = v.y;
    lds[p * 16 + lr][lc4 + 2] = v.z;
    lds[p * 16 + lr][lc4 + 3] = v.w;
  }
  __syncthreads();
  const int c = tid >> 2, rc = (tid & 3) * 8;
  ushortx8 o0, o1;
#pragma unroll
  for (int j = 0; j < 8; j++) o0[j] = f2bf(lds[rc + j][c]);
#pragma unroll
  for (int j = 0; j < 8; j++) o1[j] = f2bf(lds[rc + 32 + j][c]);
  ushort* drow = (ushort*)dst + (size_t)(c0 + c) * R + r0;
  *(ushortx8*)(drow + rc)      = o0;
  *(ushortx8*)(drow + rc + 32) = o1;
}

__global__ __launch_bounds__(256) void transpose_one(
    const float* __restrict__ src, __hip_bfloat16* __restrict__ dst, int R, int C)
{
  int tc = C >> 6;
  transpose_tile64(src, dst, R, C, blockIdx.x / tc, blockIdx.x % tc);
}

// fused per-layer weight convert+transpose (64x64 tiles).
// tiles: qkv(768x2304)=432, proj(768x768)=144, w1(768x3072)=576, w2(3072x768)=576
#define QKV_TE  ((size_t)2304*768)
#define PROJ_TE ((size_t)768*768)
#define W1_TE   ((size_t)3072*768)
#define W2_TE   ((size_t)768*3072)
#define LSTRIDE (QKV_TE + PROJ_TE + W1_TE + W2_TE)   // 7,077,888 elems

__global__ __launch_bounds__(256) void convert_weights(
    const float* __restrict__ qkv_w, const float* __restrict__ proj_w,
    const float* __restrict__ w1, const float* __restrict__ w2,
    __hip_bfloat16* __restrict__ dstBase, int layer0, size_t dstStride)
{
  int l = layer0 + blockIdx.y;
  __hip_bfloat16* d = dstBase + (size_t)blockIdx.y * dstStride;
  int tile = blockIdx.x;
  const float* src; __hip_bfloat16* dst; int R, C, t0;
  if (tile < 432)       { src = qkv_w  + (size_t)l*768*2304; dst = d;                          R=768;  C=2304; t0=tile; }
  else if (tile < 576)  { src = proj_w + (size_t)l*768*768;  dst = d + QKV_TE;                 R=768;  C=768;  t0=tile-432; }
  else if (tile < 1152) { src = w1     + (size_t)l*768*3072; dst = d + QKV_TE+PROJ_TE;         R=768;  C=3072; t0=tile-576; }
  else                  { src = w2     + (size_t)l*3072*768; dst = d + QKV_TE+PROJ_TE+W1_TE;   R=3072; C=768;  t0=tile-1152; }
  int tc = C >> 6;
  transpose_tile64(src, dst, R, C, t0 / tc, t0 % tc);
}

// ---------------------------------------------------------------------------
// bf16 MFMA GEMM: C = A(MxK) * Bt^T  (Bt is N x K row-major, pre-transposed)
// block tile 128 x TN, 4 waves, 16x16x32 MFMA, fp32 accum.
enum { EPI_NONE = 0, EPI_RESID = 1, EPI_BIAS_GELU = 2, EPI_BIAS_RESID = 3,
       EPI_EMBED = 4 };

template <int TN, int EPI, bool OUT_BF16>
__global__ __launch_bounds__(256) void gemm_mfma(
    const ushort* __restrict__ A, const ushort* __restrict__ Bt,
    const float* __restrict__ Cin, const float* __restrict__ bias,
    const float* __restrict__ pe, const int* __restrict__ mask,
    void* __restrict__ Cout, int M, int N, int K)
{
  constexpr int AM = (TN == 128) ? 4 : 2;   // A frags / wave (WM = AM*16)
  constexpr int B_LOADS = TN / 64;          // 1KB wave-loads for Bs
  __shared__ ushort As[128 * 32];
  __shared__ ushort Bs[TN * 32];

  const int tid  = threadIdx.x;
  const int wave = tid >> 6, lane = tid & 63;
  const int bm = blockIdx.y, bn = blockIdx.x;

  const int wm0 = (TN == 128) ? (wave & 1) * 64 : wave * 32;
  const int wn0 = (TN == 128) ? (wave >> 1) * 64 : 0;

  floatx4 acc[AM][4];
#pragma unroll
  for (int i = 0; i < AM; i++)
#pragma unroll
    for (int j = 0; j < 4; j++) { floatx4 z = {0.f,0.f,0.f,0.f}; acc[i][j] = z; }

  // staging source pointers: lane -> row (lane>>2), k-chunk (lane&3)*8
  const int lrow = lane >> 2, lchunk = (lane & 3) * 8;
  const ushort* aSrc[2];
  ushort*       aDst[2];
#pragma unroll
  for (int i = 0; i < 2; i++) {
    int row = bm * 128 + (wave * 2 + i) * 16 + lrow;
    row = row < M - 1 ? row : M - 1;
    aSrc[i] = A + (size_t)row * K + lchunk;
    aDst[i] = As + (wave * 2 + i) * 512;      // wave-uniform base (1KB per load)
  }
  const ushort* bSrc[B_LOADS];
  ushort*       bDst[B_LOADS];
#pragma unroll
  for (int i = 0; i < B_LOADS; i++) {
    int row = bn * TN + (wave * B_LOADS + i) * 16 + lrow;
    bSrc[i] = Bt + (size_t)row * K + lchunk;
    bDst[i] = Bs + (wave * B_LOADS + i) * 512;
  }

  for (int k0 = 0; k0 < K; k0 += 32) {
    __syncthreads();
#pragma unroll
    for (int i = 0; i < 2; i++)       async_cp16(aSrc[i] + k0, aDst[i]);
#pragma unroll
    for (int i = 0; i < B_LOADS; i++) async_cp16(bSrc[i] + k0, bDst[i]);
    __syncthreads();

    short8 af[AM], bf[4];
#pragma unroll
    for (int mt = 0; mt < AM; mt++)
      af[mt] = *(const short8*)&As[(wm0 + mt * 16 + (lane & 15)) * 32 + (lane >> 4) * 8];
#pragma unroll
    for (int nt = 0; nt < 4; nt++)
      bf[nt] = *(const short8*)&Bs[(wn0 + nt * 16 + (lane & 15)) * 32 + (lane >> 4) * 8];
#pragma unroll
    for (int mt = 0; mt < AM; mt++)
#pragma unroll
      for (int nt = 0; nt < 4; nt++)
        acc[mt][nt] = __builtin_amdgcn_mfma_f32_16x16x32_bf16(af[mt], bf[nt], acc[mt][nt], 0, 0, 0);
  }

  // epilogue: C row = wm0+mt*16+(lane>>4)*4+r, col = wn0+nt*16+(lane&15)
  const int colb = bn * TN + wn0 + (lane & 15);
  const int rq   = (lane >> 4) * 4;
#pragma unroll
  for (int mt = 0; mt < AM; mt++) {
#pragma unroll
    for (int r = 0; r < 4; r++) {
      int row = bm * 128 + wm0 + mt * 16 + rq + r;
      if (row >= M) continue;
#pragma unroll
      for (int nt = 0; nt < 4; nt++) {
        int col = colb + nt * 16;
        float u = acc[mt][nt][r];
        if (EPI == EPI_BIAS_GELU || EPI == EPI_BIAS_RESID) u += bias[col];
        if (EPI == EPI_BIAS_GELU) {
          float t3 = u * u * u;
          u = 0.5f * u * (1.f + tanhf(0.7978845608028654f * (u + 0.044715f * t3)));
        }
        if (EPI == EPI_RESID || EPI == EPI_BIAS_RESID) u += Cin[(size_t)row * N + col];
        if (EPI == EPI_EMBED) {
          int t = row % KEEPT;
          int j = mask[t];
          j = j < 0 ? 0 : (j > 196 ? 196 : j);
          if (j == 0) u = bias[col];           // class token replaces patch proj
          u += pe[(size_t)j * DIMV + col];
        }
        if (OUT_BF16)
          ((__hip_bfloat16*)Cout)[(size_t)row * N + col] = __float2bfloat16(u);
        else
          ((float*)Cout)[(size_t)row * N + col] = u;
      }
    }
  }
}

// ---------------------------------------------------------------------------
// MFMA fused attention: one block (4 waves, 256 threads) per (batch, head).
// Wave w owns q-rows [w*16, w*16+16). Q/K staged with short8 vector loads
// (72-ushort row stride = 9x16B chunks -> bank-group rotation, conflict-free
// b128 LDS writes). QK^T -> masked softmax (in-register, shfl over 16-lane
// frag groups) -> PV.
__global__ __launch_bounds__(256) void attn_mfma(
    const ushort* __restrict__ qkv, ushort* __restrict__ o)
{
  __shared__ ushort qA[64 * 72];   // Q rows (token, d)
  __shared__ ushort kB[64 * 72];   // K rows (token, d)
  __shared__ ushort vT[64 * 72];   // V^T rows (d, token)
  __shared__ ushort pA[64 * 72];   // P rows (q-token, k-token), bf16
  const int b = blockIdx.x, hh = blockIdx.y;
  const int tid = threadIdx.x;
  const int wave = tid >> 6, lane = tid & 63;
  const int fr = lane & 15, fc = lane >> 4;

  const ushort* base = qkv + (size_t)b * KEEPT * (3 * DIMV) + hh * 64;

  // Q/K: vectorized staging — 8 rows x 8 short8-lanes per wave-instr
#pragma unroll
  for (int it = 0; it < 2; it++) {
    int r  = it * 32 + wave * 8 + (lane >> 3);
    int cc = (lane & 7) * 8;
    short8 qv = {0,0,0,0,0,0,0,0};
    short8 kv = {0,0,0,0,0,0,0,0};
    if (r < KEEPT) {
      const ushort* row = base + (size_t)r * (3 * DIMV);
      qv = *(const short8*)(row + cc);
      kv = *(const short8*)(row + DIMV + cc);
    }
    *(short8*)&qA[r * 72 + cc] = qv;
    *(short8*)&kB[r * 72 + cc] = kv;
  }
  // V: transposed staging (scalar), rows strided across waves
  for (int r = wave; r < 64; r += 4) {
    ushort v = 0;
    if (r < KEEPT) v = base[(size_t)r * (3 * DIMV) + 2 * DIMV + lane];
    vT[lane * 72 + r] = v;
  }
  __syncthreads();

  const int q0 = wave * 16;
  floatx4 sacc[4];
#pragma unroll
  for (int nt = 0; nt < 4; nt++) { floatx4 z = {0.f,0.f,0.f,0.f}; sacc[nt] = z; }

#pragma unroll
  for (int kk = 0; kk < 2; kk++) {
    const int ch = kk * 32 + fc * 8;
    short8 af = *(const short8*)&qA[(q0 + fr) * 72 + ch];
#pragma unroll
    for (int nt = 0; nt < 4; nt++) {
      short8 bf = *(const short8*)&kB[(nt * 16 + fr) * 72 + ch];
      sacc[nt] = __builtin_amdgcn_mfma_f32_16x16x32_bf16(af, bf, sacc[nt], 0, 0, 0);
    }
  }

  // scale, mask cols j>=49, softmax per q-row (row lives in 16 lanes x 4 nt-regs)
  float inv[4];
#pragma unroll
  for (int r = 0; r < 4; r++) {
    float mx = -1e30f;
#pragma unroll
    for (int nt = 0; nt < 4; nt++) {
      float s = sacc[nt][r] * 0.125f;            // 1/sqrt(64)
      if (nt == 3 && fr >= 1) s = -1e30f;        // j = 48+fr >= 49
      sacc[nt][r] = s;
      mx = fmaxf(mx, s);
    }
    mx = fmaxf(mx, __shfl_xor(mx, 1, 64));
    mx = fmaxf(mx, __shfl_xor(mx, 2, 64));
    mx = fmaxf(mx, __shfl_xor(mx, 4, 64));
    mx = fmaxf(mx, __shfl_xor(mx, 8, 64));
    float sum = 0.f;
#pragma unroll
    for (int nt = 0; nt < 4; nt++) {
      float e = __expf(sacc[nt][r] - mx);
      sacc[nt][r] = e;
      sum += e;
    }
    sum += __shfl_xor(sum, 1, 64);
    sum += __shfl_xor(sum, 2, 64);
    sum += __shfl_xor(sum, 4, 64);
    sum += __shfl_xor(sum, 8, 64);
    inv[r] = 1.f / sum;
  }

  // P (unnormalized) -> LDS in A-operand (row-major) layout, bf16
#pragma unroll
  for (int r = 0; r < 4; r++)
#pragma unroll
    for (int nt = 0; nt < 4; nt++)
      pA[(q0 + fc * 4 + r) * 72 + nt * 16 + fr] = f2bf(sacc[nt][r]);
  __syncthreads();

  floatx4 oacc[4];
#pragma unroll
  for (int nt = 0; nt < 4; nt++) { floatx4 z = {0.f,0.f,0.f,0.f}; oacc[nt] = z; }

#pragma unroll
  for (int kk = 0; kk < 2; kk++) {
    const int ch = kk * 32 + fc * 8;
    short8 af = *(const short8*)&pA[(q0 + fr) * 72 + ch];
#pragma unroll
    for (int nt = 0; nt < 4; nt++) {
      short8 bf = *(const short8*)&vT[(nt * 16 + fr) * 72 + ch];
      oacc[nt] = __builtin_amdgcn_mfma_f32_16x16x32_bf16(af, bf, oacc[nt], 0, 0, 0);
    }
  }

  ushort* obase = o + (size_t)b * KEEPT * DIMV + hh * 64;
#pragma unroll
  for (int r = 0; r < 4; r++) {
    int q = q0 + fc * 4 + r;
    if (q < KEEPT) {
#pragma unroll
      for (int nt = 0; nt < 4; nt++)
        obase[(size_t)q * DIMV + nt * 16 + fr] = f2bf(oacc[nt][r] * inv[r]);
    }
  }
}

// ---------------------------------------------------------------------------
extern "C" void kernel_launch(void* const* d_in, const int* in_sizes, int n_in,
                              void* d_out, int out_size, void* d_ws, size_t ws_size,
                              hipStream_t stream)
{
  (void)in_sizes; (void)n_in; (void)out_size;
  const float* inputs = (const float*)d_in[0];
  const float* conv_w = (const float*)d_in[1];
  const float* ct     = (const float*)d_in[2];
  const float* pe     = (const float*)d_in[3];
  const float* ln1_s  = (const float*)d_in[4];
  const float* ln1_b  = (const float*)d_in[5];
  const float* qkv_w  = (const float*)d_in[6];
  const float* proj_w = (const float*)d_in[7];
  const float* ln2_s  = (const float*)d_in[8];
  const float* ln2_b  = (const float*)d_in[9];
  const float* w1     = (const float*)d_in[10];
  const float* b1     = (const float*)d_in[11];
  const float* w2     = (const float*)d_in[12];
  const float* b2     = (const float*)d_in[13];
  const int*   mask   = (const int*)d_in[14];
  float* out = (float*)d_out;

  // workspace layout (bytes):
  //   x      fp32 MTOK*768          9,633,792
  //   h      bf16 MTOK*768          4,816,896   (also apix)
  //   big    bf16 max(qkv, g)      19,267,584   (qkv: MTOK*2304, g: MTOK*3072)
  //   convT  bf16 768*768           1,179,648
  //   wbuf   bf16 LSTRIDE [*12]    14,155,776 each
  char* wsb = (char*)d_ws;
  float*          x     = (float*)wsb;
  __hip_bfloat16* h     = (__hip_bfloat16*)(wsb + 9633792);
  __hip_bfloat16* big   = (__hip_bfloat16*)(wsb + 9633792 + 4816896);
  __hip_bfloat16* convT = (__hip_bfloat16*)(wsb + 9633792 + 4816896 + 19267584);
  __hip_bfloat16* wbuf  = (__hip_bfloat16*)(wsb + 9633792 + 4816896 + 19267584 + 1179648);
  const size_t base_bytes = 9633792ull + 4816896 + 19267584 + 1179648;
  const bool all_mode = ws_size >= base_bytes + 12ull * LSTRIDE * 2;

  __hip_bfloat16* apix = h;
  __hip_bfloat16* qkv  = big;
  __hip_bfloat16* g    = big;

  dim3 blk(256);
  const int nelem = MTOK * DIMV;
  const int nblk  = (nelem + 255) / 256;
  const int mg    = (MTOK + 127) / 128;   // 25

  transpose_one<<<144, blk, 0, stream>>>(conv_w, convT, 768, 768);
  if (all_mode)
    convert_weights<<<dim3(1728, 12), blk, 0, stream>>>(
        qkv_w, proj_w, w1, w2, wbuf, 0, LSTRIDE);

  gather_patches<<<nblk, blk, 0, stream>>>(inputs, mask, apix);
  // embed GEMM with fused ct/pe epilogue (replaces finish_embed pass)
  gemm_mfma<64, EPI_EMBED, false><<<dim3(12, mg), blk, 0, stream>>>(
      (const ushort*)apix, (const ushort*)convT, nullptr, ct, pe, mask, x,
      MTOK, DIMV, DIMV);

  for (int l = 0; l < NDEPTH; l++) {
    __hip_bfloat16* wl = wbuf + (all_mode ? (size_t)l * LSTRIDE : 0);
    if (!all_mode)
      convert_weights<<<dim3(1728, 1), blk, 0, stream>>>(
          qkv_w, proj_w, w1, w2, wbuf, l, 0);
    const ushort* qkvT  = (const ushort*)wl;
    const ushort* projT = (const ushort*)(wl + QKV_TE);
    const ushort* w1T   = (const ushort*)(wl + QKV_TE + PROJ_TE);
    const ushort* w2T   = (const ushort*)(wl + QKV_TE + PROJ_TE + W1_TE);

    layernorm_k<<<MTOK, blk, 0, stream>>>(x, ln1_s + l * DIMV, ln1_b + l * DIMV, h);
    gemm_mfma<128, EPI_NONE, true><<<dim3(18, mg), blk, 0, stream>>>(
        (const ushort*)h, qkvT, nullptr, nullptr, nullptr, nullptr, qkv,
        MTOK, 3 * DIMV, DIMV);
    attn_mfma<<<dim3(BATCH, NHEADS), blk, 0, stream>>>(
        (const ushort*)qkv, (ushort*)h);
    gemm_mfma<64, EPI_RESID, false><<<dim3(12, mg), blk, 0, stream>>>(
        (const ushort*)h, projT, x, nullptr, nullptr, nullptr, x,
        MTOK, DIMV, DIMV);
    layernorm_k<<<MTOK, blk, 0, stream>>>(x, ln2_s + l * DIMV, ln2_b + l * DIMV, h);
    gemm_mfma<128, EPI_BIAS_GELU, true><<<dim3(24, mg), blk, 0, stream>>>(
        (const ushort*)h, w1T, nullptr, b1 + (size_t)l * FFV, nullptr, nullptr, g,
        MTOK, FFV, DIMV);
    float* dst = (l == NDEPTH - 1) ? out : x;
    gemm_mfma<64, EPI_BIAS_RESID, false><<<dim3(12, mg), blk, 0, stream>>>(
        (const ushort*)g, w2T, x, b2 + (size_t)l * DIMV, nullptr, nullptr, dst,
        MTOK, DIMV, FFV);
  }
}

// Round 3
// 2296.990 us; speedup vs baseline: 1.0863x; 1.0863x over previous
//
#include <hip/hip_runtime.h>
#include <hip/hip_bf16.h>
#include <math.h>

#define DIMV   768
#define BATCH  64
#define KEEPT  49
#define MTOK   (BATCH*KEEPT)   // 3136
#define NHEADS 12
#define DHEAD  64
#define FFV    3072
#define NDEPTH 12

typedef short short8 __attribute__((ext_vector_type(8)));
typedef float floatx4 __attribute__((ext_vector_type(4)));
typedef unsigned short ushort;
typedef unsigned short ushortx8 __attribute__((ext_vector_type(8)));

__device__ __forceinline__ ushort f2bf(float f) {
  __hip_bfloat16 h = __float2bfloat16(f);
  return *(ushort*)&h;
}

// ---------------------------------------------------------------------------
__device__ __forceinline__ void async_cp16(const void* g, void* l) {
  __builtin_amdgcn_global_load_lds((const __attribute__((address_space(1))) void*)g,
                                   (__attribute__((address_space(3))) void*)l,
                                   16, 0, 0);
}

// ---------------------------------------------------------------------------
// gather kept-patch pixels into (MTOK x 768) bf16 matrix
__global__ __launch_bounds__(256) void gather_patches(
    const float* __restrict__ inp, const int* __restrict__ mask,
    __hip_bfloat16* __restrict__ apix)
{
  int gid = blockIdx.x * 256 + threadIdx.x;
  if (gid >= MTOK * DIMV) return;
  int r = gid / DIMV, k = gid - r * DIMV;
  int b = r / KEEPT, t = r - b * KEEPT;
  int j = mask[t];
  j = j < 0 ? 0 : (j > 196 ? 196 : j);   // JAX clamps OOB gather indices
  float v = 0.f;
  if (j > 0) {
    int p  = j - 1, py = p / 14, px = p - py * 14;
    int ky = k / 48, rem = k - ky * 48, kx = rem / 3, c = rem - kx * 3;
    v = inp[(((b * 224) + py * 16 + ky) * 224 + px * 16 + kx) * 3 + c];
  }
  apix[gid] = __float2bfloat16(v);
}

// ---------------------------------------------------------------------------
// row layernorm fp32 -> bf16, eps=1e-9
__global__ __launch_bounds__(256) void layernorm_k(
    const float* __restrict__ x, const float* __restrict__ sc,
    const float* __restrict__ bi, __hip_bfloat16* __restrict__ out)
{
  __shared__ float red[8];
  int r = blockIdx.x;
  const float* xr = x + (size_t)r * DIMV;
  int t = threadIdx.x;
  float v[3];
  float s = 0.f, ss = 0.f;
#pragma unroll
  for (int i = 0; i < 3; i++) {
    float a = xr[t + i * 256];
    v[i] = a; s += a; ss += a * a;
  }
#pragma unroll
  for (int off = 32; off > 0; off >>= 1) {
    s  += __shfl_down(s,  off, 64);
    ss += __shfl_down(ss, off, 64);
  }
  int wave = t >> 6, lane = t & 63;
  if (lane == 0) { red[wave] = s; red[4 + wave] = ss; }
  __syncthreads();
  if (t == 0) {
    float a  = red[0] + red[1] + red[2] + red[3];
    float b2 = red[4] + red[5] + red[6] + red[7];
    float m  = a * (1.f / DIMV);
    float var = b2 * (1.f / DIMV) - m * m;
    red[0] = m;
    red[1] = rsqrtf(var + 1e-9f);
  }
  __syncthreads();
  float m = red[0], rs = red[1];
  __hip_bfloat16* outr = out + (size_t)r * DIMV;
#pragma unroll
  for (int i = 0; i < 3; i++) {
    int d = t + i * 256;
    outr[d] = __float2bfloat16((v[i] - m) * rs * sc[d] + bi[d]);
  }
}

// ---------------------------------------------------------------------------
// 64x64-tile fp32 -> bf16 transpose (dst[c][r] = bf16(src[r][c]))
__device__ __forceinline__ void transpose_tile64(
    const float* __restrict__ src, __hip_bfloat16* __restrict__ dst,
    int R, int C, int tr, int tcc)
{
  __shared__ float lds[64][65];
  const int tid = threadIdx.x;
  const int r0 = tr * 64, c0 = tcc * 64;
  const int lr = tid >> 4, lc4 = (tid & 15) * 4;
#pragma unroll
  for (int p = 0; p < 4; p++) {
    float4 v = *(const float4*)(src + (size_t)(r0 + p * 16 + lr) * C + c0 + lc4);
    lds[p * 16 + lr][lc4 + 0] = v.x;
    lds[p * 16 + lr][lc4 + 1] = v.y;
    lds[p * 16 + lr][lc4 + 2] = v.z;
    lds[p * 16 + lr][lc4 + 3] = v.w;
  }
  __syncthreads();
  const int c = tid >> 2, rc = (tid & 3) * 8;
  ushortx8 o0, o1;
#pragma unroll
  for (int j = 0; j < 8; j++) o0[j] = f2bf(lds[rc + j][c]);
#pragma unroll
  for (int j = 0; j < 8; j++) o1[j] = f2bf(lds[rc + 32 + j][c]);
  ushort* drow = (ushort*)dst + (size_t)(c0 + c) * R + r0;
  *(ushortx8*)(drow + rc)      = o0;
  *(ushortx8*)(drow + rc + 32) = o1;
}

__global__ __launch_bounds__(256) void transpose_one(
    const float* __restrict__ src, __hip_bfloat16* __restrict__ dst, int R, int C)
{
  int tc = C >> 6;
  transpose_tile64(src, dst, R, C, blockIdx.x / tc, blockIdx.x % tc);
}

// fused per-layer weight convert+transpose (64x64 tiles).
#define QKV_TE  ((size_t)2304*768)
#define PROJ_TE ((size_t)768*768)
#define W1_TE   ((size_t)3072*768)
#define W2_TE   ((size_t)768*3072)
#define LSTRIDE (QKV_TE + PROJ_TE + W1_TE + W2_TE)   // 7,077,888 elems

__global__ __launch_bounds__(256) void convert_weights(
    const float* __restrict__ qkv_w, const float* __restrict__ proj_w,
    const float* __restrict__ w1, const float* __restrict__ w2,
    __hip_bfloat16* __restrict__ dstBase, int layer0, size_t dstStride)
{
  int l = layer0 + blockIdx.y;
  __hip_bfloat16* d = dstBase + (size_t)blockIdx.y * dstStride;
  int tile = blockIdx.x;
  const float* src; __hip_bfloat16* dst; int R, C, t0;
  if (tile < 432)       { src = qkv_w  + (size_t)l*768*2304; dst = d;                          R=768;  C=2304; t0=tile; }
  else if (tile < 576)  { src = proj_w + (size_t)l*768*768;  dst = d + QKV_TE;                 R=768;  C=768;  t0=tile-432; }
  else if (tile < 1152) { src = w1     + (size_t)l*768*3072; dst = d + QKV_TE+PROJ_TE;         R=768;  C=3072; t0=tile-576; }
  else                  { src = w2     + (size_t)l*3072*768; dst = d + QKV_TE+PROJ_TE+W1_TE;   R=3072; C=768;  t0=tile-1152; }
  int tc = C >> 6;
  transpose_tile64(src, dst, R, C, t0 / tc, t0 % tc);
}

// ---------------------------------------------------------------------------
// bf16 MFMA GEMM: C = A(MxK) * Bt^T  (Bt is N x K row-major, pre-transposed)
// tile 128(M) x 64(N), BK=64, 4 waves (wave w owns rows w*32..w*32+31).
// T3 minimum-2-phase schedule (race-free, ONE barrier/iter):
//   STAGE(buf[cur^1], t+1) ; ds_read buf[cur] ; MFMA ; vmcnt(0) ; barrier
// stage-writes of buf[cur^1] at iter t are separated from its readers
// (iter t-1) by the end-of-(t-1) barrier; reads of buf[cur] are separated
// from its staging by vmcnt(0)+barrier.  LDS rows are 128B -> XOR-swizzle
// chunk16 by (row&7): global source pre-swizzled (global_load_lds writes
// linearly), reads un-swizzle (rule #21: both-sides-or-neither).
enum { EPI_NONE = 0, EPI_RESID = 1, EPI_BIAS_GELU = 2, EPI_BIAS_RESID = 3,
       EPI_EMBED = 4 };

template <int EPI, bool OUT_BF16>
__global__ __launch_bounds__(256) void gemm_mfma(
    const ushort* __restrict__ A, const ushort* __restrict__ Bt,
    const float* __restrict__ Cin, const float* __restrict__ bias,
    const float* __restrict__ pe, const int* __restrict__ mask,
    void* __restrict__ Cout, int M, int N, int K)
{
  __shared__ ushort As[2][128 * 64];   // 32 KB
  __shared__ ushort Bs[2][64 * 64];    // 16 KB

  const int tid  = threadIdx.x;
  const int wave = tid >> 6, lane = tid & 63;
  const int bm = blockIdx.y, bn = blockIdx.x;
  const int fr = lane & 15, fc = lane >> 4;

  floatx4 acc[2][4];
#pragma unroll
  for (int i = 0; i < 2; i++)
#pragma unroll
    for (int j = 0; j < 4; j++) { floatx4 z = {0.f,0.f,0.f,0.f}; acc[i][j] = z; }

  // staging: each 1KB wave-load = 8 rows x 64 k-elems (128B/row).
  // lane -> LDS row (lane>>3), LDS chunk slot (lane&7) [linear dest];
  // global source chunk pre-swizzled: (lane&7) ^ (lane>>3).
  const int lrow   = lane >> 3;
  const int lchunk = ((lane & 7) ^ lrow) * 8;   // element offset in k-slice
  const ushort* aSrc[4];                        // wave w rows w*32 .. w*32+31
#pragma unroll
  for (int i = 0; i < 4; i++) {
    int row = bm * 128 + wave * 32 + i * 8 + lrow;
    row = row < M - 1 ? row : M - 1;
    aSrc[i] = A + (size_t)row * K + lchunk;
  }
  const ushort* bSrc[2];                        // wave w rows w*16 .. w*16+15
#pragma unroll
  for (int i = 0; i < 2; i++) {
    int row = bn * 64 + wave * 16 + i * 8 + lrow;
    bSrc[i] = Bt + (size_t)row * K + lchunk;
  }

  const int NT = K >> 6;

  // prologue: stage tile 0 into buf 0 (6 vmem ops per wave)
  {
    ushort* aD = &As[0][(wave * 32) * 64];
#pragma unroll
    for (int i = 0; i < 4; i++) async_cp16(aSrc[i], aD + i * 8 * 64);
    ushort* bD = &Bs[0][(wave * 16) * 64];
#pragma unroll
    for (int i = 0; i < 2; i++) async_cp16(bSrc[i], bD + i * 8 * 64);
  }
  asm volatile("s_waitcnt vmcnt(0)" ::: "memory");
  __builtin_amdgcn_s_barrier();
  __builtin_amdgcn_sched_barrier(0);

  int cur = 0;
  for (int t = 0; t < NT; t++) {
    // issue next-tile stage FIRST (into buf[cur^1]); its previous readers
    // all finished before the barrier that ended iteration t-1.
    if (t + 1 < NT) {
      const int k0 = (t + 1) << 6;
      ushort* aD = &As[cur ^ 1][(wave * 32) * 64];
#pragma unroll
      for (int i = 0; i < 4; i++) async_cp16(aSrc[i] + k0, aD + i * 8 * 64);
      ushort* bD = &Bs[cur ^ 1][(wave * 16) * 64];
#pragma unroll
      for (int i = 0; i < 2; i++) async_cp16(bSrc[i] + k0, bD + i * 8 * 64);
    }

    const ushort* Ab = As[cur];
    const ushort* Bb = Bs[cur];
    short8 af[2][2], bf[2][4];
#pragma unroll
    for (int kk = 0; kk < 2; kk++) {
      const int cbase = kk * 4 + fc;
      const int slot  = (cbase ^ (fr & 7)) * 8;
#pragma unroll
      for (int mt = 0; mt < 2; mt++)
        af[kk][mt] = *(const short8*)&Ab[(wave * 32 + mt * 16 + fr) * 64 + slot];
#pragma unroll
      for (int nt = 0; nt < 4; nt++)
        bf[kk][nt] = *(const short8*)&Bb[(nt * 16 + fr) * 64 + slot];
    }
    __builtin_amdgcn_s_setprio(1);
#pragma unroll
    for (int kk = 0; kk < 2; kk++)
#pragma unroll
      for (int mt = 0; mt < 2; mt++)
#pragma unroll
        for (int nt = 0; nt < 4; nt++)
          acc[mt][nt] = __builtin_amdgcn_mfma_f32_16x16x32_bf16(
              af[kk][mt], bf[kk][nt], acc[mt][nt], 0, 0, 0);
    __builtin_amdgcn_s_setprio(0);

    if (t + 1 < NT) {
      asm volatile("s_waitcnt vmcnt(0)" ::: "memory");   // next tile landed
      __builtin_amdgcn_s_barrier();
      __builtin_amdgcn_sched_barrier(0);
    }
    cur ^= 1;
  }

  // epilogue: C row = wave*32+mt*16+(lane>>4)*4+r, col = bn*64+nt*16+(lane&15)
  const int colb = bn * 64 + fr;
  const int rq   = fc * 4;
#pragma unroll
  for (int mt = 0; mt < 2; mt++) {
#pragma unroll
    for (int r = 0; r < 4; r++) {
      int row = bm * 128 + wave * 32 + mt * 16 + rq + r;
      if (row >= M) continue;
#pragma unroll
      for (int nt = 0; nt < 4; nt++) {
        int col = colb + nt * 16;
        float u = acc[mt][nt][r];
        if (EPI == EPI_BIAS_GELU || EPI == EPI_BIAS_RESID) u += bias[col];
        if (EPI == EPI_BIAS_GELU) {
          float t3 = u * u * u;
          u = 0.5f * u * (1.f + tanhf(0.7978845608028654f * (u + 0.044715f * t3)));
        }
        if (EPI == EPI_RESID || EPI == EPI_BIAS_RESID) u += Cin[(size_t)row * N + col];
        if (EPI == EPI_EMBED) {
          int t = row % KEEPT;
          int j = mask[t];
          j = j < 0 ? 0 : (j > 196 ? 196 : j);
          if (j == 0) u = bias[col];           // class token replaces patch proj
          u += pe[(size_t)j * DIMV + col];
        }
        if (OUT_BF16)
          ((__hip_bfloat16*)Cout)[(size_t)row * N + col] = __float2bfloat16(u);
        else
          ((float*)Cout)[(size_t)row * N + col] = u;
      }
    }
  }
}

// ---------------------------------------------------------------------------
// MFMA fused attention: one block (4 waves, 256 threads) per (batch, head).
__global__ __launch_bounds__(256) void attn_mfma(
    const ushort* __restrict__ qkv, ushort* __restrict__ o)
{
  __shared__ ushort qA[64 * 72];   // Q rows (token, d)
  __shared__ ushort kB[64 * 72];   // K rows (token, d)
  __shared__ ushort vT[64 * 72];   // V^T rows (d, token)
  __shared__ ushort pA[64 * 72];   // P rows (q-token, k-token), bf16
  const int b = blockIdx.x, hh = blockIdx.y;
  const int tid = threadIdx.x;
  const int wave = tid >> 6, lane = tid & 63;
  const int fr = lane & 15, fc = lane >> 4;

  const ushort* base = qkv + (size_t)b * KEEPT * (3 * DIMV) + hh * 64;

#pragma unroll
  for (int it = 0; it < 2; it++) {
    int r  = it * 32 + wave * 8 + (lane >> 3);
    int cc = (lane & 7) * 8;
    short8 qv = {0,0,0,0,0,0,0,0};
    short8 kv = {0,0,0,0,0,0,0,0};
    if (r < KEEPT) {
      const ushort* row = base + (size_t)r * (3 * DIMV);
      qv = *(const short8*)(row + cc);
      kv = *(const short8*)(row + DIMV + cc);
    }
    *(short8*)&qA[r * 72 + cc] = qv;
    *(short8*)&kB[r * 72 + cc] = kv;
  }
  for (int r = wave; r < 64; r += 4) {
    ushort v = 0;
    if (r < KEEPT) v = base[(size_t)r * (3 * DIMV) + 2 * DIMV + lane];
    vT[lane * 72 + r] = v;
  }
  __syncthreads();

  const int q0 = wave * 16;
  floatx4 sacc[4];
#pragma unroll
  for (int nt = 0; nt < 4; nt++) { floatx4 z = {0.f,0.f,0.f,0.f}; sacc[nt] = z; }

#pragma unroll
  for (int kk = 0; kk < 2; kk++) {
    const int ch = kk * 32 + fc * 8;
    short8 af = *(const short8*)&qA[(q0 + fr) * 72 + ch];
#pragma unroll
    for (int nt = 0; nt < 4; nt++) {
      short8 bf = *(const short8*)&kB[(nt * 16 + fr) * 72 + ch];
      sacc[nt] = __builtin_amdgcn_mfma_f32_16x16x32_bf16(af, bf, sacc[nt], 0, 0, 0);
    }
  }

  float inv[4];
#pragma unroll
  for (int r = 0; r < 4; r++) {
    float mx = -1e30f;
#pragma unroll
    for (int nt = 0; nt < 4; nt++) {
      float s = sacc[nt][r] * 0.125f;            // 1/sqrt(64)
      if (nt == 3 && fr >= 1) s = -1e30f;        // j = 48+fr >= 49
      sacc[nt][r] = s;
      mx = fmaxf(mx, s);
    }
    mx = fmaxf(mx, __shfl_xor(mx, 1, 64));
    mx = fmaxf(mx, __shfl_xor(mx, 2, 64));
    mx = fmaxf(mx, __shfl_xor(mx, 4, 64));
    mx = fmaxf(mx, __shfl_xor(mx, 8, 64));
    float sum = 0.f;
#pragma unroll
    for (int nt = 0; nt < 4; nt++) {
      float e = __expf(sacc[nt][r] - mx);
      sacc[nt][r] = e;
      sum += e;
    }
    sum += __shfl_xor(sum, 1, 64);
    sum += __shfl_xor(sum, 2, 64);
    sum += __shfl_xor(sum, 4, 64);
    sum += __shfl_xor(sum, 8, 64);
    inv[r] = 1.f / sum;
  }

#pragma unroll
  for (int r = 0; r < 4; r++)
#pragma unroll
    for (int nt = 0; nt < 4; nt++)
      pA[(q0 + fc * 4 + r) * 72 + nt * 16 + fr] = f2bf(sacc[nt][r]);
  __syncthreads();

  floatx4 oacc[4];
#pragma unroll
  for (int nt = 0; nt < 4; nt++) { floatx4 z = {0.f,0.f,0.f,0.f}; oacc[nt] = z; }

#pragma unroll
  for (int kk = 0; kk < 2; kk++) {
    const int ch = kk * 32 + fc * 8;
    short8 af = *(const short8*)&pA[(q0 + fr) * 72 + ch];
#pragma unroll
    for (int nt = 0; nt < 4; nt++) {
      short8 bf = *(const short8*)&vT[(nt * 16 + fr) * 72 + ch];
      oacc[nt] = __builtin_amdgcn_mfma_f32_16x16x32_bf16(af, bf, oacc[nt], 0, 0, 0);
    }
  }

  ushort* obase = o + (size_t)b * KEEPT * DIMV + hh * 64;
#pragma unroll
  for (int r = 0; r < 4; r++) {
    int q = q0 + fc * 4 + r;
    if (q < KEEPT) {
#pragma unroll
      for (int nt = 0; nt < 4; nt++)
        obase[(size_t)q * DIMV + nt * 16 + fr] = f2bf(oacc[nt][r] * inv[r]);
    }
  }
}

// ---------------------------------------------------------------------------
extern "C" void kernel_launch(void* const* d_in, const int* in_sizes, int n_in,
                              void* d_out, int out_size, void* d_ws, size_t ws_size,
                              hipStream_t stream)
{
  (void)in_sizes; (void)n_in; (void)out_size;
  const float* inputs = (const float*)d_in[0];
  const float* conv_w = (const float*)d_in[1];
  const float* ct     = (const float*)d_in[2];
  const float* pe     = (const float*)d_in[3];
  const float* ln1_s  = (const float*)d_in[4];
  const float* ln1_b  = (const float*)d_in[5];
  const float* qkv_w  = (const float*)d_in[6];
  const float* proj_w = (const float*)d_in[7];
  const float* ln2_s  = (const float*)d_in[8];
  const float* ln2_b  = (const float*)d_in[9];
  const float* w1     = (const float*)d_in[10];
  const float* b1     = (const float*)d_in[11];
  const float* w2     = (const float*)d_in[12];
  const float* b2     = (const float*)d_in[13];
  const int*   mask   = (const int*)d_in[14];
  float* out = (float*)d_out;

  char* wsb = (char*)d_ws;
  float*          x     = (float*)wsb;
  __hip_bfloat16* h     = (__hip_bfloat16*)(wsb + 9633792);
  __hip_bfloat16* big   = (__hip_bfloat16*)(wsb + 9633792 + 4816896);
  __hip_bfloat16* convT = (__hip_bfloat16*)(wsb + 9633792 + 4816896 + 19267584);
  __hip_bfloat16* wbuf  = (__hip_bfloat16*)(wsb + 9633792 + 4816896 + 19267584 + 1179648);
  const size_t base_bytes = 9633792ull + 4816896 + 19267584 + 1179648;
  const bool all_mode = ws_size >= base_bytes + 12ull * LSTRIDE * 2;

  __hip_bfloat16* apix = h;
  __hip_bfloat16* qkv  = big;
  __hip_bfloat16* g    = big;

  dim3 blk(256);
  const int nelem = MTOK * DIMV;
  const int nblk  = (nelem + 255) / 256;
  const int mg    = (MTOK + 127) / 128;   // 25

  transpose_one<<<144, blk, 0, stream>>>(conv_w, convT, 768, 768);
  if (all_mode)
    convert_weights<<<dim3(1728, 12), blk, 0, stream>>>(
        qkv_w, proj_w, w1, w2, wbuf, 0, LSTRIDE);

  gather_patches<<<nblk, blk, 0, stream>>>(inputs, mask, apix);
  gemm_mfma<EPI_EMBED, false><<<dim3(12, mg), blk, 0, stream>>>(
      (const ushort*)apix, (const ushort*)convT, nullptr, ct, pe, mask, x,
      MTOK, DIMV, DIMV);

  for (int l = 0; l < NDEPTH; l++) {
    __hip_bfloat16* wl = wbuf + (all_mode ? (size_t)l * LSTRIDE : 0);
    if (!all_mode)
      convert_weights<<<dim3(1728, 1), blk, 0, stream>>>(
          qkv_w, proj_w, w1, w2, wbuf, l, 0);
    const ushort* qkvT  = (const ushort*)wl;
    const ushort* projT = (const ushort*)(wl + QKV_TE);
    const ushort* w1T   = (const ushort*)(wl + QKV_TE + PROJ_TE);
    const ushort* w2T   = (const ushort*)(wl + QKV_TE + PROJ_TE + W1_TE);

    layernorm_k<<<MTOK, blk, 0, stream>>>(x, ln1_s + l * DIMV, ln1_b + l * DIMV, h);
    gemm_mfma<EPI_NONE, true><<<dim3(36, mg), blk, 0, stream>>>(
        (const ushort*)h, qkvT, nullptr, nullptr, nullptr, nullptr, qkv,
        MTOK, 3 * DIMV, DIMV);
    attn_mfma<<<dim3(BATCH, NHEADS), blk, 0, stream>>>(
        (const ushort*)qkv, (ushort*)h);
    gemm_mfma<EPI_RESID, false><<<dim3(12, mg), blk, 0, stream>>>(
        (const ushort*)h, projT, x, nullptr, nullptr, nullptr, x,
        MTOK, DIMV, DIMV);
    layernorm_k<<<MTOK, blk, 0, stream>>>(x, ln2_s + l * DIMV, ln2_b + l * DIMV, h);
    gemm_mfma<EPI_BIAS_GELU, true><<<dim3(48, mg), blk, 0, stream>>>(
        (const ushort*)h, w1T, nullptr, b1 + (size_t)l * FFV, nullptr, nullptr, g,
        MTOK, FFV, DIMV);
    float* dst = (l == NDEPTH - 1) ? out : x;
    gemm_mfma<EPI_BIAS_RESID, false><<<dim3(12, mg), blk, 0, stream>>>(
        (const ushort*)g, w2T, x, b2 + (size_t)l * DIMV, nullptr, nullptr, dst,
        MTOK, DIMV, FFV);
  }
}

// Round 4
// 2250.518 us; speedup vs baseline: 1.1087x; 1.0206x over previous
//
#include <hip/hip_runtime.h>
#include <hip/hip_bf16.h>
#include <math.h>

#define DIMV   768
#define BATCH  64
#define KEEPT  49
#define MTOK   (BATCH*KEEPT)   // 3136
#define NHEADS 12
#define DHEAD  64
#define FFV    3072
#define NDEPTH 12

typedef short short8 __attribute__((ext_vector_type(8)));
typedef float floatx4 __attribute__((ext_vector_type(4)));
typedef unsigned short ushort;
typedef unsigned short ushortx8 __attribute__((ext_vector_type(8)));

__device__ __forceinline__ ushort f2bf(float f) {
  __hip_bfloat16 h = __float2bfloat16(f);
  return *(ushort*)&h;
}

// ---------------------------------------------------------------------------
__device__ __forceinline__ void async_cp16(const void* g, void* l) {
  __builtin_amdgcn_global_load_lds((const __attribute__((address_space(1))) void*)g,
                                   (__attribute__((address_space(3))) void*)l,
                                   16, 0, 0);
}

// ---------------------------------------------------------------------------
// gather kept-patch pixels into (MTOK x 768) bf16 matrix
__global__ __launch_bounds__(256) void gather_patches(
    const float* __restrict__ inp, const int* __restrict__ mask,
    __hip_bfloat16* __restrict__ apix)
{
  int gid = blockIdx.x * 256 + threadIdx.x;
  if (gid >= MTOK * DIMV) return;
  int r = gid / DIMV, k = gid - r * DIMV;
  int b = r / KEEPT, t = r - b * KEEPT;
  int j = mask[t];
  j = j < 0 ? 0 : (j > 196 ? 196 : j);   // JAX clamps OOB gather indices
  float v = 0.f;
  if (j > 0) {
    int p  = j - 1, py = p / 14, px = p - py * 14;
    int ky = k / 48, rem = k - ky * 48, kx = rem / 3, c = rem - kx * 3;
    v = inp[(((b * 224) + py * 16 + ky) * 224 + px * 16 + kx) * 3 + c];
  }
  apix[gid] = __float2bfloat16(v);
}

// ---------------------------------------------------------------------------
// row layernorm fp32 -> bf16, eps=1e-9
__global__ __launch_bounds__(256) void layernorm_k(
    const float* __restrict__ x, const float* __restrict__ sc,
    const float* __restrict__ bi, __hip_bfloat16* __restrict__ out)
{
  __shared__ float red[8];
  int r = blockIdx.x;
  const float* xr = x + (size_t)r * DIMV;
  int t = threadIdx.x;
  float v[3];
  float s = 0.f, ss = 0.f;
#pragma unroll
  for (int i = 0; i < 3; i++) {
    float a = xr[t + i * 256];
    v[i] = a; s += a; ss += a * a;
  }
#pragma unroll
  for (int off = 32; off > 0; off >>= 1) {
    s  += __shfl_down(s,  off, 64);
    ss += __shfl_down(ss, off, 64);
  }
  int wave = t >> 6, lane = t & 63;
  if (lane == 0) { red[wave] = s; red[4 + wave] = ss; }
  __syncthreads();
  if (t == 0) {
    float a  = red[0] + red[1] + red[2] + red[3];
    float b2 = red[4] + red[5] + red[6] + red[7];
    float m  = a * (1.f / DIMV);
    float var = b2 * (1.f / DIMV) - m * m;
    red[0] = m;
    red[1] = rsqrtf(var + 1e-9f);
  }
  __syncthreads();
  float m = red[0], rs = red[1];
  __hip_bfloat16* outr = out + (size_t)r * DIMV;
#pragma unroll
  for (int i = 0; i < 3; i++) {
    int d = t + i * 256;
    outr[d] = __float2bfloat16((v[i] - m) * rs * sc[d] + bi[d]);
  }
}

// ---------------------------------------------------------------------------
// 64x64-tile fp32 -> bf16 transpose (dst[c][r] = bf16(src[r][c]))
__device__ __forceinline__ void transpose_tile64(
    const float* __restrict__ src, __hip_bfloat16* __restrict__ dst,
    int R, int C, int tr, int tcc)
{
  __shared__ float lds[64][65];
  const int tid = threadIdx.x;
  const int r0 = tr * 64, c0 = tcc * 64;
  const int lr = tid >> 4, lc4 = (tid & 15) * 4;
#pragma unroll
  for (int p = 0; p < 4; p++) {
    float4 v = *(const float4*)(src + (size_t)(r0 + p * 16 + lr) * C + c0 + lc4);
    lds[p * 16 + lr][lc4 + 0] = v.x;
    lds[p * 16 + lr][lc4 + 1] = v.y;
    lds[p * 16 + lr][lc4 + 2] = v.z;
    lds[p * 16 + lr][lc4 + 3] = v.w;
  }
  __syncthreads();
  const int c = tid >> 2, rc = (tid & 3) * 8;
  ushortx8 o0, o1;
#pragma unroll
  for (int j = 0; j < 8; j++) o0[j] = f2bf(lds[rc + j][c]);
#pragma unroll
  for (int j = 0; j < 8; j++) o1[j] = f2bf(lds[rc + 32 + j][c]);
  ushort* drow = (ushort*)dst + (size_t)(c0 + c) * R + r0;
  *(ushortx8*)(drow + rc)      = o0;
  *(ushortx8*)(drow + rc + 32) = o1;
}

__global__ __launch_bounds__(256) void transpose_one(
    const float* __restrict__ src, __hip_bfloat16* __restrict__ dst, int R, int C)
{
  int tc = C >> 6;
  transpose_tile64(src, dst, R, C, blockIdx.x / tc, blockIdx.x % tc);
}

// fused per-layer weight convert+transpose (64x64 tiles), 4 tiles/block,
// double-buffered LDS, one barrier per tile:
//   write regs->lds[cur]; BAR; issue next-tile global loads; read lds[cur]
//   cols -> cvt -> store.
// Safety (1 barrier/iter): reads of lds[b] at iter t and writes of lds[b] at
// iter t+2 are separated by the barrier at iter t+1; data delivery of reads
// is complete before the consuming cvt (compiler lgkmcnt) which precedes the
// thread's arrival at that barrier.
#define QKV_TE  ((size_t)2304*768)
#define PROJ_TE ((size_t)768*768)
#define W1_TE   ((size_t)3072*768)
#define W2_TE   ((size_t)768*3072)
#define LSTRIDE (QKV_TE + PROJ_TE + W1_TE + W2_TE)   // 7,077,888 elems
#define CW_TPG  4                                    // tiles per block

struct CwTile { const float* s; ushort* d; int R, C; };

__global__ __launch_bounds__(256) void convert_weights(
    const float* __restrict__ qkv_w, const float* __restrict__ proj_w,
    const float* __restrict__ w1, const float* __restrict__ w2,
    __hip_bfloat16* __restrict__ dstBase, int layer0, size_t dstStride)
{
  __shared__ float lds[2][64][65];
  const int l = layer0 + blockIdx.y;
  __hip_bfloat16* dl = dstBase + (size_t)blockIdx.y * dstStride;
  const int tid = threadIdx.x;
  const int lr = tid >> 4, lc4 = (tid & 15) * 4;   // load mapping
  const int oc = tid >> 2, orc = (tid & 3) * 8;    // store mapping

  auto resolve = [&](int tile) -> CwTile {
    const float* src; __hip_bfloat16* dst; int R, C, t0;
    if (tile < 432)       { src = qkv_w  + (size_t)l*768*2304; dst = dl;                        R=768;  C=2304; t0=tile; }
    else if (tile < 576)  { src = proj_w + (size_t)l*768*768;  dst = dl + QKV_TE;               R=768;  C=768;  t0=tile-432; }
    else if (tile < 1152) { src = w1     + (size_t)l*768*3072; dst = dl + QKV_TE+PROJ_TE;       R=768;  C=3072; t0=tile-576; }
    else                  { src = w2     + (size_t)l*3072*768; dst = dl + QKV_TE+PROJ_TE+W1_TE; R=3072; C=768;  t0=tile-1152; }
    int tc = C >> 6, tr = t0 / tc, tcc = t0 % tc;
    CwTile r;
    r.s = src + (size_t)(tr * 64) * C + tcc * 64;
    r.d = (ushort*)dst + (size_t)(tcc * 64) * R + tr * 64;
    r.R = R; r.C = C;
    return r;
  };

  const int tbase = blockIdx.x * CW_TPG;
  CwTile cti = resolve(tbase);
  float4 rv[4];
#pragma unroll
  for (int p = 0; p < 4; p++)
    rv[p] = *(const float4*)(cti.s + (size_t)(p * 16 + lr) * cti.C + lc4);

  int cur = 0;
  for (int ti = 0; ti < CW_TPG; ti++) {
#pragma unroll
    for (int p = 0; p < 4; p++) {
      lds[cur][p * 16 + lr][lc4 + 0] = rv[p].x;
      lds[cur][p * 16 + lr][lc4 + 1] = rv[p].y;
      lds[cur][p * 16 + lr][lc4 + 2] = rv[p].z;
      lds[cur][p * 16 + lr][lc4 + 3] = rv[p].w;
    }
    __syncthreads();
    CwTile nti;
    if (ti + 1 < CW_TPG) {
      nti = resolve(tbase + ti + 1);
#pragma unroll
      for (int p = 0; p < 4; p++)
        rv[p] = *(const float4*)(nti.s + (size_t)(p * 16 + lr) * nti.C + lc4);
    }
    ushortx8 o0, o1;
#pragma unroll
    for (int j = 0; j < 8; j++) o0[j] = f2bf(lds[cur][orc + j][oc]);
#pragma unroll
    for (int j = 0; j < 8; j++) o1[j] = f2bf(lds[cur][orc + 32 + j][oc]);
    ushort* drow = cti.d + (size_t)oc * cti.R;
    *(ushortx8*)(drow + orc)      = o0;
    *(ushortx8*)(drow + orc + 32) = o1;
    if (ti + 1 < CW_TPG) cti = nti;
    cur ^= 1;
  }
}

// ---------------------------------------------------------------------------
// bf16 MFMA GEMM (SMALL): C = A(MxK) * Bt^T, tile 128(M) x 64(N), BK=64,
// 4 waves (wave w owns rows w*32..w*32+31).  T3 2-phase schedule (verified
// R3): STAGE(buf[cur^1],t+1); ds_read buf[cur]; MFMA; vmcnt(0); barrier.
// LDS rows 128B -> XOR-swizzle chunk16 by (row&7), source pre-swizzled.
enum { EPI_NONE = 0, EPI_RESID = 1, EPI_BIAS_GELU = 2, EPI_BIAS_RESID = 3,
       EPI_EMBED = 4 };

template <int EPI, bool OUT_BF16>
__device__ __forceinline__ void gemm_epilogue_elem(
    float u, int row, int col, int N,
    const float* __restrict__ Cin, const float* __restrict__ bias,
    const float* __restrict__ pe, const int* __restrict__ mask,
    void* __restrict__ Cout)
{
  if (EPI == EPI_BIAS_GELU || EPI == EPI_BIAS_RESID) u += bias[col];
  if (EPI == EPI_BIAS_GELU) {
    float t3 = u * u * u;
    u = 0.5f * u * (1.f + tanhf(0.7978845608028654f * (u + 0.044715f * t3)));
  }
  if (EPI == EPI_RESID || EPI == EPI_BIAS_RESID) u += Cin[(size_t)row * N + col];
  if (EPI == EPI_EMBED) {
    int t = row % KEEPT;
    int j = mask[t];
    j = j < 0 ? 0 : (j > 196 ? 196 : j);
    if (j == 0) u = bias[col];           // class token replaces patch proj
    u += pe[(size_t)j * DIMV + col];
  }
  if (OUT_BF16)
    ((__hip_bfloat16*)Cout)[(size_t)row * N + col] = __float2bfloat16(u);
  else
    ((float*)Cout)[(size_t)row * N + col] = u;
}

template <int EPI, bool OUT_BF16>
__global__ __launch_bounds__(256) void gemm_mfma(
    const ushort* __restrict__ A, const ushort* __restrict__ Bt,
    const float* __restrict__ Cin, const float* __restrict__ bias,
    const float* __restrict__ pe, const int* __restrict__ mask,
    void* __restrict__ Cout, int M, int N, int K)
{
  __shared__ ushort As[2][128 * 64];   // 32 KB
  __shared__ ushort Bs[2][64 * 64];    // 16 KB

  const int tid  = threadIdx.x;
  const int wave = tid >> 6, lane = tid & 63;
  const int bm = blockIdx.y, bn = blockIdx.x;
  const int fr = lane & 15, fc = lane >> 4;

  floatx4 acc[2][4];
#pragma unroll
  for (int i = 0; i < 2; i++)
#pragma unroll
    for (int j = 0; j < 4; j++) { floatx4 z = {0.f,0.f,0.f,0.f}; acc[i][j] = z; }

  const int lrow   = lane >> 3;
  const int lchunk = ((lane & 7) ^ lrow) * 8;   // pre-swizzled source chunk
  const ushort* aSrc[4];
#pragma unroll
  for (int i = 0; i < 4; i++) {
    int row = bm * 128 + wave * 32 + i * 8 + lrow;
    row = row < M - 1 ? row : M - 1;
    aSrc[i] = A + (size_t)row * K + lchunk;
  }
  const ushort* bSrc[2];
#pragma unroll
  for (int i = 0; i < 2; i++) {
    int row = bn * 64 + wave * 16 + i * 8 + lrow;
    bSrc[i] = Bt + (size_t)row * K + lchunk;
  }

  const int NT = K >> 6;
  {
    ushort* aD = &As[0][(wave * 32) * 64];
#pragma unroll
    for (int i = 0; i < 4; i++) async_cp16(aSrc[i], aD + i * 8 * 64);
    ushort* bD = &Bs[0][(wave * 16) * 64];
#pragma unroll
    for (int i = 0; i < 2; i++) async_cp16(bSrc[i], bD + i * 8 * 64);
  }
  asm volatile("s_waitcnt vmcnt(0)" ::: "memory");
  __builtin_amdgcn_s_barrier();
  __builtin_amdgcn_sched_barrier(0);

  int cur = 0;
  for (int t = 0; t < NT; t++) {
    if (t + 1 < NT) {
      const int k0 = (t + 1) << 6;
      ushort* aD = &As[cur ^ 1][(wave * 32) * 64];
#pragma unroll
      for (int i = 0; i < 4; i++) async_cp16(aSrc[i] + k0, aD + i * 8 * 64);
      ushort* bD = &Bs[cur ^ 1][(wave * 16) * 64];
#pragma unroll
      for (int i = 0; i < 2; i++) async_cp16(bSrc[i] + k0, bD + i * 8 * 64);
    }

    const ushort* Ab = As[cur];
    const ushort* Bb = Bs[cur];
    short8 af[2][2], bf[2][4];
#pragma unroll
    for (int kk = 0; kk < 2; kk++) {
      const int cbase = kk * 4 + fc;
      const int slot  = (cbase ^ (fr & 7)) * 8;
#pragma unroll
      for (int mt = 0; mt < 2; mt++)
        af[kk][mt] = *(const short8*)&Ab[(wave * 32 + mt * 16 + fr) * 64 + slot];
#pragma unroll
      for (int nt = 0; nt < 4; nt++)
        bf[kk][nt] = *(const short8*)&Bb[(nt * 16 + fr) * 64 + slot];
    }
    __builtin_amdgcn_s_setprio(1);
#pragma unroll
    for (int kk = 0; kk < 2; kk++)
#pragma unroll
      for (int mt = 0; mt < 2; mt++)
#pragma unroll
        for (int nt = 0; nt < 4; nt++)
          acc[mt][nt] = __builtin_amdgcn_mfma_f32_16x16x32_bf16(
              af[kk][mt], bf[kk][nt], acc[mt][nt], 0, 0, 0);
    __builtin_amdgcn_s_setprio(0);

    if (t + 1 < NT) {
      asm volatile("s_waitcnt vmcnt(0)" ::: "memory");
      __builtin_amdgcn_s_barrier();
      __builtin_amdgcn_sched_barrier(0);
    }
    cur ^= 1;
  }

  const int colb = bn * 64 + fr;
  const int rq   = fc * 4;
#pragma unroll
  for (int mt = 0; mt < 2; mt++)
#pragma unroll
    for (int r = 0; r < 4; r++) {
      int row = bm * 128 + wave * 32 + mt * 16 + rq + r;
      if (row >= M) continue;
#pragma unroll
      for (int nt = 0; nt < 4; nt++)
        gemm_epilogue_elem<EPI, OUT_BF16>(acc[mt][nt][r], row, colb + nt * 16,
                                          N, Cin, bias, pe, mask, Cout);
    }
}

// ---------------------------------------------------------------------------
// bf16 MFMA GEMM (BIG): tile 128(M) x 128(N), BK=64, 8 waves (512 thr) in a
// 2(M) x 4(N) wave grid; each wave computes 64x32.  Same verified 2-phase
// schedule + XOR swizzle as SMALL.  Used for the big-N GEMMs (qkv, fc1).
template <int EPI, bool OUT_BF16>
__global__ __launch_bounds__(512) void gemm_big(
    const ushort* __restrict__ A, const ushort* __restrict__ Bt,
    const float* __restrict__ Cin, const float* __restrict__ bias,
    const float* __restrict__ pe, const int* __restrict__ mask,
    void* __restrict__ Cout, int M, int N, int K)
{
  __shared__ ushort As[2][128 * 64];   // 32 KB
  __shared__ ushort Bs[2][128 * 64];   // 32 KB

  const int tid  = threadIdx.x;
  const int wave = tid >> 6, lane = tid & 63;
  const int bm = blockIdx.y, bn = blockIdx.x;
  const int fr = lane & 15, fc = lane >> 4;
  const int wm0 = (wave >> 2) * 64, wn0 = (wave & 3) * 32;

  floatx4 acc[4][2];
#pragma unroll
  for (int i = 0; i < 4; i++)
#pragma unroll
    for (int j = 0; j < 2; j++) { floatx4 z = {0.f,0.f,0.f,0.f}; acc[i][j] = z; }

  const int lrow   = lane >> 3;
  const int lchunk = ((lane & 7) ^ lrow) * 8;
  const ushort* aSrc[2];               // wave stages A rows wave*16..+15
#pragma unroll
  for (int i = 0; i < 2; i++) {
    int row = bm * 128 + wave * 16 + i * 8 + lrow;
    row = row < M - 1 ? row : M - 1;
    aSrc[i] = A + (size_t)row * K + lchunk;
  }
  const ushort* bSrc[2];               // wave stages B rows wave*16..+15
#pragma unroll
  for (int i = 0; i < 2; i++) {
    int row = bn * 128 + wave * 16 + i * 8 + lrow;
    bSrc[i] = Bt + (size_t)row * K + lchunk;
  }

  const int NT = K >> 6;
  {
    ushort* aD = &As[0][(wave * 16) * 64];
#pragma unroll
    for (int i = 0; i < 2; i++) async_cp16(aSrc[i], aD + i * 8 * 64);
    ushort* bD = &Bs[0][(wave * 16) * 64];
#pragma unroll
    for (int i = 0; i < 2; i++) async_cp16(bSrc[i], bD + i * 8 * 64);
  }
  asm volatile("s_waitcnt vmcnt(0)" ::: "memory");
  __builtin_amdgcn_s_barrier();
  __builtin_amdgcn_sched_barrier(0);

  int cur = 0;
  for (int t = 0; t < NT; t++) {
    if (t + 1 < NT) {
      const int k0 = (t + 1) << 6;
      ushort* aD = &As[cur ^ 1][(wave * 16) * 64];
#pragma unroll
      for (int i = 0; i < 2; i++) async_cp16(aSrc[i] + k0, aD + i * 8 * 64);
      ushort* bD = &Bs[cur ^ 1][(wave * 16) * 64];
#pragma unroll
      for (int i = 0; i < 2; i++) async_cp16(bSrc[i] + k0, bD + i * 8 * 64);
    }

    const ushort* Ab = As[cur];
    const ushort* Bb = Bs[cur];
    short8 af[2][4], bf[2][2];
#pragma unroll
    for (int kk = 0; kk < 2; kk++) {
      const int cbase = kk * 4 + fc;
      const int slot  = (cbase ^ (fr & 7)) * 8;
#pragma unroll
      for (int mt = 0; mt < 4; mt++)
        af[kk][mt] = *(const short8*)&Ab[(wm0 + mt * 16 + fr) * 64 + slot];
#pragma unroll
      for (int nt = 0; nt < 2; nt++)
        bf[kk][nt] = *(const short8*)&Bb[(wn0 + nt * 16 + fr) * 64 + slot];
    }
    __builtin_amdgcn_s_setprio(1);
#pragma unroll
    for (int kk = 0; kk < 2; kk++)
#pragma unroll
      for (int mt = 0; mt < 4; mt++)
#pragma unroll
        for (int nt = 0; nt < 2; nt++)
          acc[mt][nt] = __builtin_amdgcn_mfma_f32_16x16x32_bf16(
              af[kk][mt], bf[kk][nt], acc[mt][nt], 0, 0, 0);
    __builtin_amdgcn_s_setprio(0);

    if (t + 1 < NT) {
      asm volatile("s_waitcnt vmcnt(0)" ::: "memory");
      __builtin_amdgcn_s_barrier();
      __builtin_amdgcn_sched_barrier(0);
    }
    cur ^= 1;
  }

  const int colb = bn * 128 + wn0 + fr;
  const int rq   = fc * 4;
#pragma unroll
  for (int mt = 0; mt < 4; mt++)
#pragma unroll
    for (int r = 0; r < 4; r++) {
      int row = bm * 128 + wm0 + mt * 16 + rq + r;
      if (row >= M) continue;
#pragma unroll
      for (int nt = 0; nt < 2; nt++)
        gemm_epilogue_elem<EPI, OUT_BF16>(acc[mt][nt][r], row, colb + nt * 16,
                                          N, Cin, bias, pe, mask, Cout);
    }
}

// ---------------------------------------------------------------------------
// MFMA fused attention: one block (4 waves, 256 threads) per (batch, head).
__global__ __launch_bounds__(256) void attn_mfma(
    const ushort* __restrict__ qkv, ushort* __restrict__ o)
{
  __shared__ ushort qA[64 * 72];   // Q rows (token, d)
  __shared__ ushort kB[64 * 72];   // K rows (token, d)
  __shared__ ushort vT[64 * 72];   // V^T rows (d, token)
  __shared__ ushort pA[64 * 72];   // P rows (q-token, k-token), bf16
  const int b = blockIdx.x, hh = blockIdx.y;
  const int tid = threadIdx.x;
  const int wave = tid >> 6, lane = tid & 63;
  const int fr = lane & 15, fc = lane >> 4;

  const ushort* base = qkv + (size_t)b * KEEPT * (3 * DIMV) + hh * 64;

#pragma unroll
  for (int it = 0; it < 2; it++) {
    int r  = it * 32 + wave * 8 + (lane >> 3);
    int cc = (lane & 7) * 8;
    short8 qv = {0,0,0,0,0,0,0,0};
    short8 kv = {0,0,0,0,0,0,0,0};
    if (r < KEEPT) {
      const ushort* row = base + (size_t)r * (3 * DIMV);
      qv = *(const short8*)(row + cc);
      kv = *(const short8*)(row + DIMV + cc);
    }
    *(short8*)&qA[r * 72 + cc] = qv;
    *(short8*)&kB[r * 72 + cc] = kv;
  }
  for (int r = wave; r < 64; r += 4) {
    ushort v = 0;
    if (r < KEEPT) v = base[(size_t)r * (3 * DIMV) + 2 * DIMV + lane];
    vT[lane * 72 + r] = v;
  }
  __syncthreads();

  const int q0 = wave * 16;
  floatx4 sacc[4];
#pragma unroll
  for (int nt = 0; nt < 4; nt++) { floatx4 z = {0.f,0.f,0.f,0.f}; sacc[nt] = z; }

#pragma unroll
  for (int kk = 0; kk < 2; kk++) {
    const int ch = kk * 32 + fc * 8;
    short8 af = *(const short8*)&qA[(q0 + fr) * 72 + ch];
#pragma unroll
    for (int nt = 0; nt < 4; nt++) {
      short8 bf = *(const short8*)&kB[(nt * 16 + fr) * 72 + ch];
      sacc[nt] = __builtin_amdgcn_mfma_f32_16x16x32_bf16(af, bf, sacc[nt], 0, 0, 0);
    }
  }

  float inv[4];
#pragma unroll
  for (int r = 0; r < 4; r++) {
    float mx = -1e30f;
#pragma unroll
    for (int nt = 0; nt < 4; nt++) {
      float s = sacc[nt][r] * 0.125f;            // 1/sqrt(64)
      if (nt == 3 && fr >= 1) s = -1e30f;        // j = 48+fr >= 49
      sacc[nt][r] = s;
      mx = fmaxf(mx, s);
    }
    mx = fmaxf(mx, __shfl_xor(mx, 1, 64));
    mx = fmaxf(mx, __shfl_xor(mx, 2, 64));
    mx = fmaxf(mx, __shfl_xor(mx, 4, 64));
    mx = fmaxf(mx, __shfl_xor(mx, 8, 64));
    float sum = 0.f;
#pragma unroll
    for (int nt = 0; nt < 4; nt++) {
      float e = __expf(sacc[nt][r] - mx);
      sacc[nt][r] = e;
      sum += e;
    }
    sum += __shfl_xor(sum, 1, 64);
    sum += __shfl_xor(sum, 2, 64);
    sum += __shfl_xor(sum, 4, 64);
    sum += __shfl_xor(sum, 8, 64);
    inv[r] = 1.f / sum;
  }

#pragma unroll
  for (int r = 0; r < 4; r++)
#pragma unroll
    for (int nt = 0; nt < 4; nt++)
      pA[(q0 + fc * 4 + r) * 72 + nt * 16 + fr] = f2bf(sacc[nt][r]);
  __syncthreads();

  floatx4 oacc[4];
#pragma unroll
  for (int nt = 0; nt < 4; nt++) { floatx4 z = {0.f,0.f,0.f,0.f}; oacc[nt] = z; }

#pragma unroll
  for (int kk = 0; kk < 2; kk++) {
    const int ch = kk * 32 + fc * 8;
    short8 af = *(const short8*)&pA[(q0 + fr) * 72 + ch];
#pragma unroll
    for (int nt = 0; nt < 4; nt++) {
      short8 bf = *(const short8*)&vT[(nt * 16 + fr) * 72 + ch];
      oacc[nt] = __builtin_amdgcn_mfma_f32_16x16x32_bf16(af, bf, oacc[nt], 0, 0, 0);
    }
  }

  ushort* obase = o + (size_t)b * KEEPT * DIMV + hh * 64;
#pragma unroll
  for (int r = 0; r < 4; r++) {
    int q = q0 + fc * 4 + r;
    if (q < KEEPT) {
#pragma unroll
      for (int nt = 0; nt < 4; nt++)
        obase[(size_t)q * DIMV + nt * 16 + fr] = f2bf(oacc[nt][r] * inv[r]);
    }
  }
}

// ---------------------------------------------------------------------------
extern "C" void kernel_launch(void* const* d_in, const int* in_sizes, int n_in,
                              void* d_out, int out_size, void* d_ws, size_t ws_size,
                              hipStream_t stream)
{
  (void)in_sizes; (void)n_in; (void)out_size;
  const float* inputs = (const float*)d_in[0];
  const float* conv_w = (const float*)d_in[1];
  const float* ct     = (const float*)d_in[2];
  const float* pe     = (const float*)d_in[3];
  const float* ln1_s  = (const float*)d_in[4];
  const float* ln1_b  = (const float*)d_in[5];
  const float* qkv_w  = (const float*)d_in[6];
  const float* proj_w = (const float*)d_in[7];
  const float* ln2_s  = (const float*)d_in[8];
  const float* ln2_b  = (const float*)d_in[9];
  const float* w1     = (const float*)d_in[10];
  const float* b1     = (const float*)d_in[11];
  const float* w2     = (const float*)d_in[12];
  const float* b2     = (const float*)d_in[13];
  const int*   mask   = (const int*)d_in[14];
  float* out = (float*)d_out;

  char* wsb = (char*)d_ws;
  float*          x     = (float*)wsb;
  __hip_bfloat16* h     = (__hip_bfloat16*)(wsb + 9633792);
  __hip_bfloat16* big   = (__hip_bfloat16*)(wsb + 9633792 + 4816896);
  __hip_bfloat16* convT = (__hip_bfloat16*)(wsb + 9633792 + 4816896 + 19267584);
  __hip_bfloat16* wbuf  = (__hip_bfloat16*)(wsb + 9633792 + 4816896 + 19267584 + 1179648);
  const size_t base_bytes = 9633792ull + 4816896 + 19267584 + 1179648;
  const bool all_mode = ws_size >= base_bytes + 12ull * LSTRIDE * 2;

  __hip_bfloat16* apix = h;
  __hip_bfloat16* qkv  = big;
  __hip_bfloat16* g    = big;

  dim3 blk(256);
  dim3 blk2(512);
  const int nelem = MTOK * DIMV;
  const int nblk  = (nelem + 255) / 256;
  const int mg    = (MTOK + 127) / 128;   // 25

  transpose_one<<<144, blk, 0, stream>>>(conv_w, convT, 768, 768);
  if (all_mode)
    convert_weights<<<dim3(1728 / CW_TPG, 12), blk, 0, stream>>>(
        qkv_w, proj_w, w1, w2, wbuf, 0, LSTRIDE);

  gather_patches<<<nblk, blk, 0, stream>>>(inputs, mask, apix);
  gemm_mfma<EPI_EMBED, false><<<dim3(12, mg), blk, 0, stream>>>(
      (const ushort*)apix, (const ushort*)convT, nullptr, ct, pe, mask, x,
      MTOK, DIMV, DIMV);

  for (int l = 0; l < NDEPTH; l++) {
    __hip_bfloat16* wl = wbuf + (all_mode ? (size_t)l * LSTRIDE : 0);
    if (!all_mode)
      convert_weights<<<dim3(1728 / CW_TPG, 1), blk, 0, stream>>>(
          qkv_w, proj_w, w1, w2, wbuf, l, 0);
    const ushort* qkvT  = (const ushort*)wl;
    const ushort* projT = (const ushort*)(wl + QKV_TE);
    const ushort* w1T   = (const ushort*)(wl + QKV_TE + PROJ_TE);
    const ushort* w2T   = (const ushort*)(wl + QKV_TE + PROJ_TE + W1_TE);

    layernorm_k<<<MTOK, blk, 0, stream>>>(x, ln1_s + l * DIMV, ln1_b + l * DIMV, h);
    gemm_big<EPI_NONE, true><<<dim3(18, mg), blk2, 0, stream>>>(
        (const ushort*)h, qkvT, nullptr, nullptr, nullptr, nullptr, qkv,
        MTOK, 3 * DIMV, DIMV);
    attn_mfma<<<dim3(BATCH, NHEADS), blk, 0, stream>>>(
        (const ushort*)qkv, (ushort*)h);
    gemm_mfma<EPI_RESID, false><<<dim3(12, mg), blk, 0, stream>>>(
        (const ushort*)h, projT, x, nullptr, nullptr, nullptr, x,
        MTOK, DIMV, DIMV);
    layernorm_k<<<MTOK, blk, 0, stream>>>(x, ln2_s + l * DIMV, ln2_b + l * DIMV, h);
    gemm_big<EPI_BIAS_GELU, true><<<dim3(24, mg), blk2, 0, stream>>>(
        (const ushort*)h, w1T, nullptr, b1 + (size_t)l * FFV, nullptr, nullptr, g,
        MTOK, FFV, DIMV);
    float* dst = (l == NDEPTH - 1) ? out : x;
    gemm_mfma<EPI_BIAS_RESID, false><<<dim3(12, mg), blk, 0, stream>>>(
        (const ushort*)g, w2T, x, b2 + (size_t)l * DIMV, nullptr, nullptr, dst,
        MTOK, DIMV, FFV);
  }
}